// Round 15
// baseline (164.833 us; speedup 1.0000x reference)
//
#include <hip/hip_runtime.h>
#include <hip/hip_bf16.h>

// Fused: QKV proj (+bias) -> RoPE(Q,K) -> MHA softmax -> out proj (+bias)
// B=8 S=1024 D=1024 H=16 Dk=64.
// R15 = R13 revert (GEMMs: zero-LDS direct-fragment, 2-deep P/Q prefetch,
// setprio, 1D XCD m-chunk -- NOTE: QKV's XCD->m mapping co-locates its K/V
// writes with attn's XCD->bh reads; R14's 2D remap broke this, costing 5us)
// + attn in 4-wave/256-thr blocks (512 blocks, 2 co-resident/CU) for
// cross-block overlap instead of one monolithic 8-wave block.

typedef __bf16 bf16_t;
typedef __bf16 bf16x8 __attribute__((ext_vector_type(8)));
typedef float  f32x4  __attribute__((ext_vector_type(4)));

static __device__ __forceinline__ f32x4 mfma16(bf16x8 a, bf16x8 b, f32x4 c) {
  return __builtin_amdgcn_mfma_f32_16x16x32_bf16(a, b, c, 0, 0, 0);
}

#if __has_builtin(__builtin_amdgcn_exp2f)
#define EXP2F(x) __builtin_amdgcn_exp2f(x)
#else
#define EXP2F(x) exp2f(x)
#endif

// ---------------- prep (single kernel): granule casts + rope table --------
__global__ void k_prep(const float* __restrict__ x, const float* __restrict__ Wq,
                       const float* __restrict__ Wk, const float* __restrict__ Wv,
                       const float* __restrict__ Wo, const int* __restrict__ pos,
                       bf16_t* __restrict__ Xf, bf16_t* __restrict__ Wf,
                       float2* __restrict__ rt) {
  const int bid = blockIdx.x;
  const int t = threadIdx.x;
  if (bid < 4096) {                     // x -> Xf granules (8192x1024)
    int g = bid * 256 + t;
    int rg = g >> 11, kt = (g >> 6) & 31, lane = g & 63;
    int m = rg * 16 + (lane & 15);
    int k = kt * 32 + (lane >> 4) * 8;
    const float* s = x + (size_t)m * 1024 + k;
    float4 v0 = *(const float4*)s;
    float4 v1 = *(const float4*)(s + 4);
    union { bf16_t b[8]; } pk;
    pk.b[0] = (bf16_t)v0.x; pk.b[1] = (bf16_t)v0.y; pk.b[2] = (bf16_t)v0.z; pk.b[3] = (bf16_t)v0.w;
    pk.b[4] = (bf16_t)v1.x; pk.b[5] = (bf16_t)v1.y; pk.b[6] = (bf16_t)v1.z; pk.b[7] = (bf16_t)v1.w;
    __builtin_memcpy(Xf + (size_t)g * 8, pk.b, 16);
  } else if (bid < 6144) {              // W -> Wf granules (rg: Wq|Wk|Wv|Wo)
    int g = (bid - 4096) * 256 + t;
    int rg = g >> 11, kt = (g >> 6) & 31, lane = g & 63;
    const float* src = (rg < 64) ? Wq : (rg < 128) ? Wk : (rg < 192) ? Wv : Wo;
    int row = (rg & 63) * 16 + (lane & 15);
    int k = kt * 32 + (lane >> 4) * 8;
    const float* s = src + (size_t)row * 1024 + k;
    float4 v0 = *(const float4*)s;
    float4 v1 = *(const float4*)(s + 4);
    union { bf16_t b[8]; } pk;
    pk.b[0] = (bf16_t)v0.x; pk.b[1] = (bf16_t)v0.y; pk.b[2] = (bf16_t)v0.z; pk.b[3] = (bf16_t)v0.w;
    pk.b[4] = (bf16_t)v1.x; pk.b[5] = (bf16_t)v1.y; pk.b[6] = (bf16_t)v1.z; pk.b[7] = (bf16_t)v1.w;
    __builtin_memcpy(Wf + (size_t)g * 8, pk.b, 16);
  } else {                              // rope table
    int rb = bid - 6144;                // [0,128)
    int s = rb * 8 + (t >> 5);
    int f = t & 31;
    float p = (float)pos[s];
    float inv = powf(10000.0f, -(float)(2 * f) / 64.0f);
    float a = p * inv;
    rt[s * 32 + f] = make_float2(cosf(a), sinf(a));
  }
}

// ==== direct-fragment GEMM body: 128x256 tile, 8 waves (2M x 4N) [R13] ====
#define GEMM_DIRECT_BODY(AfBase, BfBase)                                       \
  const int t = threadIdx.x;                                                   \
  const int lane = t & 63, w = t >> 6;                                         \
  const int hi = lane >> 4, c = lane & 15;                                     \
  const int wm = w >> 2, wn = w & 3;                                           \
  const bf16_t* Ab = (AfBase) + (size_t)((i0 >> 4) + wm * 4) * 16384 + lane * 8; \
  const bf16_t* Bb = (BfBase) + (size_t)((e0 >> 4) + wn * 4) * 16384 + lane * 8; \
  bf16x8 pa0, pa1, pa2, pa3, pb0, pb1, pb2, pb3;                               \
  bf16x8 qa0, qa1, qa2, qa3, qb0, qb1, qb2, qb3;                               \
  f32x4 acc[4][4] = {};                                                        \
  auto loadP = [&](int kt) {                                                   \
    pa0 = *(const bf16x8*)(Ab + kt * 512);                                     \
    pa1 = *(const bf16x8*)(Ab + 16384 + kt * 512);                             \
    pa2 = *(const bf16x8*)(Ab + 32768 + kt * 512);                             \
    pa3 = *(const bf16x8*)(Ab + 49152 + kt * 512);                             \
    pb0 = *(const bf16x8*)(Bb + kt * 512);                                     \
    pb1 = *(const bf16x8*)(Bb + 16384 + kt * 512);                             \
    pb2 = *(const bf16x8*)(Bb + 32768 + kt * 512);                             \
    pb3 = *(const bf16x8*)(Bb + 49152 + kt * 512);                             \
  };                                                                           \
  auto loadQ = [&](int kt) {                                                   \
    qa0 = *(const bf16x8*)(Ab + kt * 512);                                     \
    qa1 = *(const bf16x8*)(Ab + 16384 + kt * 512);                             \
    qa2 = *(const bf16x8*)(Ab + 32768 + kt * 512);                             \
    qa3 = *(const bf16x8*)(Ab + 49152 + kt * 512);                             \
    qb0 = *(const bf16x8*)(Bb + kt * 512);                                     \
    qb1 = *(const bf16x8*)(Bb + 16384 + kt * 512);                             \
    qb2 = *(const bf16x8*)(Bb + 32768 + kt * 512);                             \
    qb3 = *(const bf16x8*)(Bb + 49152 + kt * 512);                             \
  };                                                                           \
  auto compP = [&]() {                                                         \
    bf16x8 a_[4] = {pa0, pa1, pa2, pa3}, b_[4] = {pb0, pb1, pb2, pb3};         \
    __builtin_amdgcn_s_setprio(1);                                             \
    _Pragma("unroll") for (int fr = 0; fr < 4; ++fr)                           \
      _Pragma("unroll") for (int nc = 0; nc < 4; ++nc)                         \
        acc[fr][nc] = mfma16(a_[fr], b_[nc], acc[fr][nc]);                     \
    __builtin_amdgcn_s_setprio(0);                                             \
  };                                                                           \
  auto compQ = [&]() {                                                         \
    bf16x8 a_[4] = {qa0, qa1, qa2, qa3}, b_[4] = {qb0, qb1, qb2, qb3};         \
    __builtin_amdgcn_s_setprio(1);                                             \
    _Pragma("unroll") for (int fr = 0; fr < 4; ++fr)                           \
      _Pragma("unroll") for (int nc = 0; nc < 4; ++nc)                         \
        acc[fr][nc] = mfma16(a_[fr], b_[nc], acc[fr][nc]);                     \
    __builtin_amdgcn_s_setprio(0);                                             \
  };                                                                           \
  loadP(0);                                                                    \
  loadQ(1);                                                                    \
  _Pragma("unroll 3")                                                          \
  for (int jj = 0; jj < 15; ++jj) {                                            \
    compP(); loadP(jj * 2 + 2);                                                \
    compQ(); loadQ(jj * 2 + 3);                                                \
  }                                                                            \
  compP();                                                                     \
  compQ();

// ---------------- fused QKV GEMM: N=3072, 768 blocks, XCD m-chunk ---------
// XCD x owns m [1024x, 1024x+1024) = batch x  ==> writes K/V for bh
// [16x,16x+16), which attn on XCD x reads (producer-consumer L2 warmth).
__global__ __launch_bounds__(512) void k_gemm_qkv(
    const bf16_t* __restrict__ Xf, const bf16_t* __restrict__ Wf,
    const float* __restrict__ bq, const float* __restrict__ bk,
    const float* __restrict__ bv, const float2* __restrict__ rt,
    bf16_t* __restrict__ Qh, bf16_t* __restrict__ Kg, bf16_t* __restrict__ Vg) {
  const int bid = blockIdx.x;
  const int x = bid & 7, q = bid >> 3;           // q in [0,96)
  const int i0 = (x * 8 + (q & 7)) * 128;
  const int e0 = (q >> 3) * 256;

  GEMM_DIRECT_BODY(Xf, Wf)

  const int z = e0 >> 10;                       // 0:Q 1:K 2:V
  const int ez0 = (e0 & 1023) + wn * 64;        // multiple of 64
  const int h = ez0 >> 6;
  const float* bias = (z == 0) ? bq : (z == 1) ? bk : bv;
  if (z == 2) {
    // V -> V^T granule (R12 ledger).
#pragma unroll
    for (int fr = 0; fr < 4; ++fr) {
      int i = i0 + wm * 64 + fr * 16 + hi * 4;
      int b_ = i >> 10, sbase = i & 1023;
      int bhv = b_ * 16 + h;
      int lane_ = c | (((sbase >> 3) & 3) << 4);
#pragma unroll
      for (int nc = 0; nc < 4; ++nc) {
        float bv_ = bias[ez0 + nc * 16 + c];
        union { bf16_t b[4]; } pk;
#pragma unroll
        for (int r = 0; r < 4; ++r) pk.b[r] = (bf16_t)(acc[fr][nc][r] + bv_);
        size_t g = (size_t)(bhv * 4 + nc) * 32 + (sbase >> 5);
        __builtin_memcpy(&Vg[g * 512 + lane_ * 8 + (sbase & 7)], pk.b, 8);
      }
    }
  } else if (z == 0) {
    // Q row-major with rope; folds 1/sqrt(64)*log2(e) (exp2-domain softmax).
    const float scl = 0.18033688011112042f;
#pragma unroll
    for (int fr = 0; fr < 4; ++fr) {
      int i = i0 + wm * 64 + fr * 16 + hi * 4;
      int b_ = i >> 10, sbase = i & 1023;
      size_t obase = (size_t)((b_ * 16 + h) * 1024);
#pragma unroll
      for (int nc = 0; nc < 2; ++nc) {
        int f = nc * 16 + c;
        float b1_ = bias[ez0 + f], b2_ = bias[ez0 + f + 32];
#pragma unroll
        for (int r = 0; r < 4; ++r) {
          int s = sbase + r;
          float2 cs = rt[s * 32 + f];
          float q1 = acc[fr][nc][r] + b1_;
          float q2 = acc[fr][nc + 2][r] + b2_;
          Qh[(obase + s) * 64 + f] = (bf16_t)((q1 * cs.x - q2 * cs.y) * scl);
          Qh[(obase + s) * 64 + f + 32] = (bf16_t)((q1 * cs.y + q2 * cs.x) * scl);
        }
      }
    }
  } else {
    // K -> granule with rope (R12 ledger).
#pragma unroll
    for (int fr = 0; fr < 4; ++fr) {
      int i = i0 + wm * 64 + fr * 16 + hi * 4;
      int b_ = i >> 10, sbase = i & 1023;
      bf16_t* gb = Kg + (size_t)((b_ * 16 + h) * 64 + (sbase >> 4)) * 1024;
#pragma unroll
      for (int nc = 0; nc < 2; ++nc) {
        int f = nc * 16 + c;
        float b1_ = bias[ez0 + f], b2_ = bias[ez0 + f + 32];
        int laneHi = (nc * 2 + (c >> 3)) << 4;
#pragma unroll
        for (int r = 0; r < 4; ++r) {
          int s = sbase + r;
          float2 cs = rt[s * 32 + f];
          float q1 = acc[fr][nc][r] + b1_;
          float q2 = acc[fr][nc + 2][r] + b2_;
          size_t off = (size_t)((hi * 4 + r) | laneHi) * 8 + (c & 7);
          gb[off] = (bf16_t)(q1 * cs.x - q2 * cs.y);
          gb[off + 512] = (bf16_t)(q1 * cs.y + q2 * cs.x);
        }
      }
    }
  }
}

// ---------------- out projection: 256 blocks, XCD m-chunk [R13] -----------
__global__ __launch_bounds__(512) void k_gemm_out(
    const bf16_t* __restrict__ Ogf, const bf16_t* __restrict__ Wf,
    const float* __restrict__ bo, float* __restrict__ out) {
  const int bid = blockIdx.x;
  const int x = bid & 7, q = bid >> 3;           // q in [0,32)
  const int i0 = (x * 8 + (q & 7)) * 128;
  const int e0 = (q >> 3) * 256;
  const bf16_t* WfO = Wf + (size_t)192 * 16384;

  GEMM_DIRECT_BODY(Ogf, WfO)

#pragma unroll
  for (int fr = 0; fr < 4; ++fr) {
    int i = i0 + wm * 64 + fr * 16 + hi * 4;
#pragma unroll
    for (int nc = 0; nc < 4; ++nc) {
      int e = e0 + wn * 64 + nc * 16 + c;
      float bv_ = bo[e];
#pragma unroll
      for (int r = 0; r < 4; ++r)
        out[(size_t)(i + r) * 1024 + e] = acc[fr][nc][r] + bv_;
    }
  }
}

// ---------------- flash attention (R15: 4-wave blocks, 2/CU) ---------------
// 512 blocks x 256 thr (4 waves). XCD x owns bh [16x,16x+16) (matches QKV
// producer mapping). Wave = 64 q-rows (4 sets of 16); per-wave structure
// identical to R13. Two co-resident blocks/CU desynchronize and overlap
// QK^T / softmax / PV phases (barrier-free -> free drift).
__global__ __launch_bounds__(256) void k_attn(
    const bf16_t* __restrict__ Qh, const bf16_t* __restrict__ Kg,
    const bf16_t* __restrict__ Vg, bf16_t* __restrict__ Ogf) {
  __shared__ alignas(16) char PL[4][2048];
  const int t = threadIdx.x;
  const int lane = t & 63, w = t >> 6;           // w in [0,4)
  const int hi = lane >> 4, c = lane & 15;
  const int bid = blockIdx.x;
  const int wg = (bid & 7) * 64 + (bid >> 3);    // XCD x -> bh [16x,16x+16)
  const int bh = wg >> 2, qt = wg & 3;
  const int q0 = qt * 256 + w * 64;
  const size_t qbase = (size_t)bh * 64 * 1024;

  const bf16_t* Kb = Kg + (size_t)bh * 65536 + lane * 8;
  const bf16_t* Vb = Vg + (size_t)bh * 65536 + lane * 8;

  bf16x8 qf[4][2];
#pragma unroll
  for (int ss = 0; ss < 4; ++ss)
#pragma unroll
    for (int kk = 0; kk < 2; ++kk)
      qf[ss][kk] = *(const bf16x8*)&Qh[qbase + (size_t)(q0 + ss * 16 + c) * 64 +
                                       kk * 32 + hi * 8];

  f32x4 o[4][4] = {};
  float m_[4] = {-1e30f, -1e30f, -1e30f, -1e30f};
  float l_[4] = {0.f, 0.f, 0.f, 0.f};
  char* const plw = &PL[w][0];

  bf16x8 kp[8], kq[8], vv[8];
#pragma unroll
  for (int i = 0; i < 8; ++i) kp[i] = *(const bf16x8*)(Kb + i * 512);

#define SM_PV(ST, M, L, O)                                                     \
  {                                                                            \
    float pmax = -1e30f;                                                       \
    _Pragma("unroll") for (int ni = 0; ni < 4; ++ni)                           \
      _Pragma("unroll") for (int r = 0; r < 4; ++r)                            \
        pmax = fmaxf(pmax, ST[ni][r]);                                         \
    pmax = fmaxf(pmax, __shfl_xor(pmax, 16));                                  \
    pmax = fmaxf(pmax, __shfl_xor(pmax, 32));                                  \
    float mn = fmaxf(M, pmax);                                                 \
    float scale = EXP2F(M - mn);                                               \
    M = mn;                                                                    \
    float psum = 0.f;                                                          \
    _Pragma("unroll") for (int ni = 0; ni < 4; ++ni) {                         \
      union { bf16_t b[4]; } pk;                                               \
      _Pragma("unroll") for (int r = 0; r < 4; ++r) {                          \
        float p = EXP2F(ST[ni][r] - mn);                                       \
        psum += p;                                                             \
        pk.b[r] = (bf16_t)p;                                                   \
      }                                                                        \
      __builtin_memcpy(plw + (ni * 2 + (hi >> 1)) * 256 + c * 16 + (hi & 1) * 8, \
                       pk.b, 8);                                               \
    }                                                                          \
    psum += __shfl_xor(psum, 16);                                              \
    psum += __shfl_xor(psum, 32);                                              \
    L = L * scale + psum;                                                      \
    _Pragma("unroll") for (int od = 0; od < 4; ++od)                           \
      _Pragma("unroll") for (int r = 0; r < 4; ++r) O[od][r] *= scale;         \
    bf16x8 pa[2];                                                              \
    __builtin_memcpy(&pa[0], plw + lane * 16, 16);                             \
    __builtin_memcpy(&pa[1], plw + 1024 + lane * 16, 16);                      \
    _Pragma("unroll") for (int od = 0; od < 4; ++od)                           \
      _Pragma("unroll") for (int kk = 0; kk < 2; ++kk)                         \
        O[od] = mfma16(vv[od * 2 + kk], pa[kk], O[od]);                        \
  }

#define ATTN_TILE(KS, KN, KT)                                                  \
  {                                                                            \
    _Pragma("unroll") for (int i = 0; i < 8; ++i)                              \
      vv[i] = *(const bf16x8*)(Vb + ((i >> 1) * 32 + (KT) * 2 + (i & 1)) * 512); \
    _Pragma("unroll") for (int ss = 0; ss < 4; ++ss) {                         \
      f32x4 st[4] = {};                                                        \
      _Pragma("unroll") for (int ni = 0; ni < 4; ++ni)                         \
        _Pragma("unroll") for (int kk = 0; kk < 2; ++kk)                       \
          st[ni] = mfma16(KS[ni * 2 + kk], qf[ss][kk], st[ni]);                \
      if (ss == 0 && (KT) + 1 < 16) {                                          \
        _Pragma("unroll") for (int i = 0; i < 8; ++i)                          \
          KN[i] = *(const bf16x8*)(Kb + (((KT) + 1) * 8 + i) * 512);           \
      }                                                                        \
      SM_PV(st, m_[ss], l_[ss], o[ss])                                         \
    }                                                                          \
  }

  for (int jj = 0; jj < 8; ++jj) {
    ATTN_TILE(kp, kq, jj * 2);
    ATTN_TILE(kq, kp, jj * 2 + 1);
  }
#undef ATTN_TILE
#undef SM_PV

  // Epilogue -> Ogf granule layout (4 sets; set ss occupies rowgroup rg0+ss).
  int b_ = bh >> 4, h = bh & 15;
  int rg0 = ((b_ << 10) + q0) >> 4;
#pragma unroll
  for (int ss = 0; ss < 4; ++ss) {
    float iv = 1.f / l_[ss];
#pragma unroll
    for (int od = 0; od < 4; ++od) {
      union { bf16_t b[4]; } pk;
#pragma unroll
      for (int r = 0; r < 4; ++r) pk.b[r] = (bf16_t)(o[ss][od][r] * iv);
      int kt2 = (h << 1) + (od >> 1);
      int lp = ((od & 1) * 2 + (hi >> 1)) * 16 + c;
      int el = (hi & 1) * 4;
      __builtin_memcpy(&Ogf[((size_t)((rg0 + ss) * 32 + kt2) * 64 + lp) * 8 + el],
                       pk.b, 8);
    }
  }
}

extern "C" void kernel_launch(void* const* d_in, const int* in_sizes, int n_in,
                              void* d_out, int out_size, void* d_ws, size_t ws_size,
                              hipStream_t stream) {
  const float* x = (const float*)d_in[0];
  const int* pos = (const int*)d_in[1];
  const float* Wq = (const float*)d_in[2];
  const float* bq = (const float*)d_in[3];
  const float* Wk = (const float*)d_in[4];
  const float* bk = (const float*)d_in[5];
  const float* Wv = (const float*)d_in[6];
  const float* bv = (const float*)d_in[7];
  const float* Wo = (const float*)d_in[8];
  const float* bo = (const float*)d_in[9];
  float* out = (float*)d_out;

  // ws: [0,16M) Xf (granule; reused as Ogf) | [16M,24M) Wf (granule)
  //     [24M,40M) Vg (V^T granule) | [42M,..) rope table.
  // Qh (row-major) + Kg (granule) live in d_out (16MB each).
  char* ws = (char*)d_ws;
  bf16_t* Xf = (bf16_t*)ws;
  bf16_t* Wf = (bf16_t*)(ws + (16u << 20));
  bf16_t* Vg = (bf16_t*)(ws + (24u << 20));
  float2* rt = (float2*)(ws + (42u << 20));
  bf16_t* Qh = (bf16_t*)d_out;
  bf16_t* Kg = (bf16_t*)d_out + (size_t)8 * 1024 * 1024;
  bf16_t* Ogf = Xf;

  k_prep<<<6272, 256, 0, stream>>>(x, Wq, Wk, Wv, Wo, pos, Xf, Wf, rt);
  k_gemm_qkv<<<768, 512, 0, stream>>>(Xf, Wf, bq, bk, bv, rt, Qh, Kg, Vg);
  k_attn<<<512, 256, 0, stream>>>(Qh, Kg, Vg, Ogf);
  k_gemm_out<<<256, 512, 0, stream>>>(Ogf, Wf, bo, out);
}

// Round 16
// 143.474 us; speedup vs baseline: 1.1489x; 1.1489x over previous
//
#include <hip/hip_runtime.h>
#include <hip/hip_bf16.h>

// Fused: QKV proj (+bias) -> RoPE(Q,K) -> MHA softmax -> out proj (+bias)
// B=8 S=1024 D=1024 H=16 Dk=64.
// R16 = R13 exact (best: 152.9us; GEMMs zero-LDS direct-fragment + setprio,
// XCD m-chunk producer/consumer-aligned; attn 8-wave/256-block barrier-free,
// 4 q-sets/wave) + T13 defer-max in attn softmax: skip O/L rescale when
// __all(pmax <= M + 8) (wave-uniform). R14 (3-deep prefetch, 2D chunk) and
// R15 (4-wave attn blocks) both REGRESSED and are abandoned.

typedef __bf16 bf16_t;
typedef __bf16 bf16x8 __attribute__((ext_vector_type(8)));
typedef float  f32x4  __attribute__((ext_vector_type(4)));

static __device__ __forceinline__ f32x4 mfma16(bf16x8 a, bf16x8 b, f32x4 c) {
  return __builtin_amdgcn_mfma_f32_16x16x32_bf16(a, b, c, 0, 0, 0);
}

#if __has_builtin(__builtin_amdgcn_exp2f)
#define EXP2F(x) __builtin_amdgcn_exp2f(x)
#else
#define EXP2F(x) exp2f(x)
#endif

// ---------------- prep (single kernel): granule casts + rope table --------
__global__ void k_prep(const float* __restrict__ x, const float* __restrict__ Wq,
                       const float* __restrict__ Wk, const float* __restrict__ Wv,
                       const float* __restrict__ Wo, const int* __restrict__ pos,
                       bf16_t* __restrict__ Xf, bf16_t* __restrict__ Wf,
                       float2* __restrict__ rt) {
  const int bid = blockIdx.x;
  const int t = threadIdx.x;
  if (bid < 4096) {                     // x -> Xf granules (8192x1024)
    int g = bid * 256 + t;
    int rg = g >> 11, kt = (g >> 6) & 31, lane = g & 63;
    int m = rg * 16 + (lane & 15);
    int k = kt * 32 + (lane >> 4) * 8;
    const float* s = x + (size_t)m * 1024 + k;
    float4 v0 = *(const float4*)s;
    float4 v1 = *(const float4*)(s + 4);
    union { bf16_t b[8]; } pk;
    pk.b[0] = (bf16_t)v0.x; pk.b[1] = (bf16_t)v0.y; pk.b[2] = (bf16_t)v0.z; pk.b[3] = (bf16_t)v0.w;
    pk.b[4] = (bf16_t)v1.x; pk.b[5] = (bf16_t)v1.y; pk.b[6] = (bf16_t)v1.z; pk.b[7] = (bf16_t)v1.w;
    __builtin_memcpy(Xf + (size_t)g * 8, pk.b, 16);
  } else if (bid < 6144) {              // W -> Wf granules (rg: Wq|Wk|Wv|Wo)
    int g = (bid - 4096) * 256 + t;
    int rg = g >> 11, kt = (g >> 6) & 31, lane = g & 63;
    const float* src = (rg < 64) ? Wq : (rg < 128) ? Wk : (rg < 192) ? Wv : Wo;
    int row = (rg & 63) * 16 + (lane & 15);
    int k = kt * 32 + (lane >> 4) * 8;
    const float* s = src + (size_t)row * 1024 + k;
    float4 v0 = *(const float4*)s;
    float4 v1 = *(const float4*)(s + 4);
    union { bf16_t b[8]; } pk;
    pk.b[0] = (bf16_t)v0.x; pk.b[1] = (bf16_t)v0.y; pk.b[2] = (bf16_t)v0.z; pk.b[3] = (bf16_t)v0.w;
    pk.b[4] = (bf16_t)v1.x; pk.b[5] = (bf16_t)v1.y; pk.b[6] = (bf16_t)v1.z; pk.b[7] = (bf16_t)v1.w;
    __builtin_memcpy(Wf + (size_t)g * 8, pk.b, 16);
  } else {                              // rope table
    int rb = bid - 6144;                // [0,128)
    int s = rb * 8 + (t >> 5);
    int f = t & 31;
    float p = (float)pos[s];
    float inv = powf(10000.0f, -(float)(2 * f) / 64.0f);
    float a = p * inv;
    rt[s * 32 + f] = make_float2(cosf(a), sinf(a));
  }
}

// ==== direct-fragment GEMM body: 128x256 tile, 8 waves (2M x 4N) [R13] ====
#define GEMM_DIRECT_BODY(AfBase, BfBase)                                       \
  const int t = threadIdx.x;                                                   \
  const int lane = t & 63, w = t >> 6;                                         \
  const int hi = lane >> 4, c = lane & 15;                                     \
  const int wm = w >> 2, wn = w & 3;                                           \
  const bf16_t* Ab = (AfBase) + (size_t)((i0 >> 4) + wm * 4) * 16384 + lane * 8; \
  const bf16_t* Bb = (BfBase) + (size_t)((e0 >> 4) + wn * 4) * 16384 + lane * 8; \
  bf16x8 pa0, pa1, pa2, pa3, pb0, pb1, pb2, pb3;                               \
  bf16x8 qa0, qa1, qa2, qa3, qb0, qb1, qb2, qb3;                               \
  f32x4 acc[4][4] = {};                                                        \
  auto loadP = [&](int kt) {                                                   \
    pa0 = *(const bf16x8*)(Ab + kt * 512);                                     \
    pa1 = *(const bf16x8*)(Ab + 16384 + kt * 512);                             \
    pa2 = *(const bf16x8*)(Ab + 32768 + kt * 512);                             \
    pa3 = *(const bf16x8*)(Ab + 49152 + kt * 512);                             \
    pb0 = *(const bf16x8*)(Bb + kt * 512);                                     \
    pb1 = *(const bf16x8*)(Bb + 16384 + kt * 512);                             \
    pb2 = *(const bf16x8*)(Bb + 32768 + kt * 512);                             \
    pb3 = *(const bf16x8*)(Bb + 49152 + kt * 512);                             \
  };                                                                           \
  auto loadQ = [&](int kt) {                                                   \
    qa0 = *(const bf16x8*)(Ab + kt * 512);                                     \
    qa1 = *(const bf16x8*)(Ab + 16384 + kt * 512);                             \
    qa2 = *(const bf16x8*)(Ab + 32768 + kt * 512);                             \
    qa3 = *(const bf16x8*)(Ab + 49152 + kt * 512);                             \
    qb0 = *(const bf16x8*)(Bb + kt * 512);                                     \
    qb1 = *(const bf16x8*)(Bb + 16384 + kt * 512);                             \
    qb2 = *(const bf16x8*)(Bb + 32768 + kt * 512);                             \
    qb3 = *(const bf16x8*)(Bb + 49152 + kt * 512);                             \
  };                                                                           \
  auto compP = [&]() {                                                         \
    bf16x8 a_[4] = {pa0, pa1, pa2, pa3}, b_[4] = {pb0, pb1, pb2, pb3};         \
    __builtin_amdgcn_s_setprio(1);                                             \
    _Pragma("unroll") for (int fr = 0; fr < 4; ++fr)                           \
      _Pragma("unroll") for (int nc = 0; nc < 4; ++nc)                         \
        acc[fr][nc] = mfma16(a_[fr], b_[nc], acc[fr][nc]);                     \
    __builtin_amdgcn_s_setprio(0);                                             \
  };                                                                           \
  auto compQ = [&]() {                                                         \
    bf16x8 a_[4] = {qa0, qa1, qa2, qa3}, b_[4] = {qb0, qb1, qb2, qb3};         \
    __builtin_amdgcn_s_setprio(1);                                             \
    _Pragma("unroll") for (int fr = 0; fr < 4; ++fr)                           \
      _Pragma("unroll") for (int nc = 0; nc < 4; ++nc)                         \
        acc[fr][nc] = mfma16(a_[fr], b_[nc], acc[fr][nc]);                     \
    __builtin_amdgcn_s_setprio(0);                                             \
  };                                                                           \
  loadP(0);                                                                    \
  loadQ(1);                                                                    \
  _Pragma("unroll 3")                                                          \
  for (int jj = 0; jj < 15; ++jj) {                                            \
    compP(); loadP(jj * 2 + 2);                                                \
    compQ(); loadQ(jj * 2 + 3);                                                \
  }                                                                            \
  compP();                                                                     \
  compQ();

// ---------------- fused QKV GEMM: N=3072, 768 blocks, XCD m-chunk ---------
// XCD x owns m [1024x, 1024x+1024) = batch x  ==> writes K/V for bh
// [16x,16x+16), which attn on XCD x reads (producer-consumer L2 warmth;
// R14's 2D remap broke this and cost 5us).
__global__ __launch_bounds__(512) void k_gemm_qkv(
    const bf16_t* __restrict__ Xf, const bf16_t* __restrict__ Wf,
    const float* __restrict__ bq, const float* __restrict__ bk,
    const float* __restrict__ bv, const float2* __restrict__ rt,
    bf16_t* __restrict__ Qh, bf16_t* __restrict__ Kg, bf16_t* __restrict__ Vg) {
  const int bid = blockIdx.x;
  const int x = bid & 7, q = bid >> 3;           // q in [0,96)
  const int i0 = (x * 8 + (q & 7)) * 128;
  const int e0 = (q >> 3) * 256;

  GEMM_DIRECT_BODY(Xf, Wf)

  const int z = e0 >> 10;                       // 0:Q 1:K 2:V
  const int ez0 = (e0 & 1023) + wn * 64;        // multiple of 64
  const int h = ez0 >> 6;
  const float* bias = (z == 0) ? bq : (z == 1) ? bk : bv;
  if (z == 2) {
    // V -> V^T granule (R12 ledger).
#pragma unroll
    for (int fr = 0; fr < 4; ++fr) {
      int i = i0 + wm * 64 + fr * 16 + hi * 4;
      int b_ = i >> 10, sbase = i & 1023;
      int bhv = b_ * 16 + h;
      int lane_ = c | (((sbase >> 3) & 3) << 4);
#pragma unroll
      for (int nc = 0; nc < 4; ++nc) {
        float bv_ = bias[ez0 + nc * 16 + c];
        union { bf16_t b[4]; } pk;
#pragma unroll
        for (int r = 0; r < 4; ++r) pk.b[r] = (bf16_t)(acc[fr][nc][r] + bv_);
        size_t g = (size_t)(bhv * 4 + nc) * 32 + (sbase >> 5);
        __builtin_memcpy(&Vg[g * 512 + lane_ * 8 + (sbase & 7)], pk.b, 8);
      }
    }
  } else if (z == 0) {
    // Q row-major with rope; folds 1/sqrt(64)*log2(e) (exp2-domain softmax).
    const float scl = 0.18033688011112042f;
#pragma unroll
    for (int fr = 0; fr < 4; ++fr) {
      int i = i0 + wm * 64 + fr * 16 + hi * 4;
      int b_ = i >> 10, sbase = i & 1023;
      size_t obase = (size_t)((b_ * 16 + h) * 1024);
#pragma unroll
      for (int nc = 0; nc < 2; ++nc) {
        int f = nc * 16 + c;
        float b1_ = bias[ez0 + f], b2_ = bias[ez0 + f + 32];
#pragma unroll
        for (int r = 0; r < 4; ++r) {
          int s = sbase + r;
          float2 cs = rt[s * 32 + f];
          float q1 = acc[fr][nc][r] + b1_;
          float q2 = acc[fr][nc + 2][r] + b2_;
          Qh[(obase + s) * 64 + f] = (bf16_t)((q1 * cs.x - q2 * cs.y) * scl);
          Qh[(obase + s) * 64 + f + 32] = (bf16_t)((q1 * cs.y + q2 * cs.x) * scl);
        }
      }
    }
  } else {
    // K -> granule with rope (R12 ledger).
#pragma unroll
    for (int fr = 0; fr < 4; ++fr) {
      int i = i0 + wm * 64 + fr * 16 + hi * 4;
      int b_ = i >> 10, sbase = i & 1023;
      bf16_t* gb = Kg + (size_t)((b_ * 16 + h) * 64 + (sbase >> 4)) * 1024;
#pragma unroll
      for (int nc = 0; nc < 2; ++nc) {
        int f = nc * 16 + c;
        float b1_ = bias[ez0 + f], b2_ = bias[ez0 + f + 32];
        int laneHi = (nc * 2 + (c >> 3)) << 4;
#pragma unroll
        for (int r = 0; r < 4; ++r) {
          int s = sbase + r;
          float2 cs = rt[s * 32 + f];
          float q1 = acc[fr][nc][r] + b1_;
          float q2 = acc[fr][nc + 2][r] + b2_;
          size_t off = (size_t)((hi * 4 + r) | laneHi) * 8 + (c & 7);
          gb[off] = (bf16_t)(q1 * cs.x - q2 * cs.y);
          gb[off + 512] = (bf16_t)(q1 * cs.y + q2 * cs.x);
        }
      }
    }
  }
}

// ---------------- out projection: 256 blocks, XCD m-chunk [R13] -----------
__global__ __launch_bounds__(512) void k_gemm_out(
    const bf16_t* __restrict__ Ogf, const bf16_t* __restrict__ Wf,
    const float* __restrict__ bo, float* __restrict__ out) {
  const int bid = blockIdx.x;
  const int x = bid & 7, q = bid >> 3;           // q in [0,32)
  const int i0 = (x * 8 + (q & 7)) * 128;
  const int e0 = (q >> 3) * 256;
  const bf16_t* WfO = Wf + (size_t)192 * 16384;

  GEMM_DIRECT_BODY(Ogf, WfO)

#pragma unroll
  for (int fr = 0; fr < 4; ++fr) {
    int i = i0 + wm * 64 + fr * 16 + hi * 4;
#pragma unroll
    for (int nc = 0; nc < 4; ++nc) {
      int e = e0 + wn * 64 + nc * 16 + c;
      float bv_ = bo[e];
#pragma unroll
      for (int r = 0; r < 4; ++r)
        out[(size_t)(i + r) * 1024 + e] = acc[fr][nc][r] + bv_;
    }
  }
}

// ---------------- flash attention (R13 shape + T13 defer-max) --------------
// 256 blocks x 512 thr (8 waves; R15's 4-wave split regressed -- occupancy
// collapsed to 10%). XCD x owns bh [16x,16x+16). Wave = 64 q-rows (4 sets).
// T13: skip O/L rescale when __all(pmax <= M + 8) -- P bounded by 2^8, same
// relative bf16 precision (m239; HK THR=8).
__global__ __launch_bounds__(512) void k_attn(
    const bf16_t* __restrict__ Qh, const bf16_t* __restrict__ Kg,
    const bf16_t* __restrict__ Vg, bf16_t* __restrict__ Ogf) {
  __shared__ alignas(16) char PL[8][2048];
  const int t = threadIdx.x;
  const int lane = t & 63, w = t >> 6;
  const int hi = lane >> 4, c = lane & 15;
  const int bid = blockIdx.x;
  const int wg = (bid & 7) * 32 + (bid >> 3);    // XCD x -> bh [16x,16x+16)
  const int bh = wg >> 1, half = wg & 1;
  const int q0 = half * 512 + w * 64;
  const size_t qbase = (size_t)bh * 64 * 1024;

  const bf16_t* Kb = Kg + (size_t)bh * 65536 + lane * 8;
  const bf16_t* Vb = Vg + (size_t)bh * 65536 + lane * 8;

  bf16x8 qf[4][2];
#pragma unroll
  for (int ss = 0; ss < 4; ++ss)
#pragma unroll
    for (int kk = 0; kk < 2; ++kk)
      qf[ss][kk] = *(const bf16x8*)&Qh[qbase + (size_t)(q0 + ss * 16 + c) * 64 +
                                       kk * 32 + hi * 8];

  f32x4 o[4][4] = {};
  float m_[4] = {-1e30f, -1e30f, -1e30f, -1e30f};
  float l_[4] = {0.f, 0.f, 0.f, 0.f};
  char* const plw = &PL[w][0];

  bf16x8 kp[8], kq[8], vv[8];
#pragma unroll
  for (int i = 0; i < 8; ++i) kp[i] = *(const bf16x8*)(Kb + i * 512);

#define SM_PV(ST, M, L, O)                                                     \
  {                                                                            \
    float pmax = -1e30f;                                                       \
    _Pragma("unroll") for (int ni = 0; ni < 4; ++ni)                           \
      _Pragma("unroll") for (int r = 0; r < 4; ++r)                            \
        pmax = fmaxf(pmax, ST[ni][r]);                                         \
    pmax = fmaxf(pmax, __shfl_xor(pmax, 16));                                  \
    pmax = fmaxf(pmax, __shfl_xor(pmax, 32));                                  \
    if (!__all(pmax <= M + 8.0f)) {        /* T13 defer-max (THR=8) */         \
      float mn = fmaxf(M, pmax);                                               \
      float sc = EXP2F(M - mn);                                                \
      M = mn;                                                                  \
      L *= sc;                                                                 \
      _Pragma("unroll") for (int od = 0; od < 4; ++od)                         \
        _Pragma("unroll") for (int r = 0; r < 4; ++r) O[od][r] *= sc;          \
    }                                                                          \
    float psum = 0.f;                                                          \
    _Pragma("unroll") for (int ni = 0; ni < 4; ++ni) {                         \
      union { bf16_t b[4]; } pk;                                               \
      _Pragma("unroll") for (int r = 0; r < 4; ++r) {                          \
        float p = EXP2F(ST[ni][r] - M);                                        \
        psum += p;                                                             \
        pk.b[r] = (bf16_t)p;                                                   \
      }                                                                        \
      __builtin_memcpy(plw + (ni * 2 + (hi >> 1)) * 256 + c * 16 + (hi & 1) * 8, \
                       pk.b, 8);                                               \
    }                                                                          \
    psum += __shfl_xor(psum, 16);                                              \
    psum += __shfl_xor(psum, 32);                                              \
    L += psum;                                                                 \
    bf16x8 pa[2];                                                              \
    __builtin_memcpy(&pa[0], plw + lane * 16, 16);                             \
    __builtin_memcpy(&pa[1], plw + 1024 + lane * 16, 16);                      \
    _Pragma("unroll") for (int od = 0; od < 4; ++od)                           \
      _Pragma("unroll") for (int kk = 0; kk < 2; ++kk)                         \
        O[od] = mfma16(vv[od * 2 + kk], pa[kk], O[od]);                        \
  }

#define ATTN_TILE(KS, KN, KT)                                                  \
  {                                                                            \
    _Pragma("unroll") for (int i = 0; i < 8; ++i)                              \
      vv[i] = *(const bf16x8*)(Vb + ((i >> 1) * 32 + (KT) * 2 + (i & 1)) * 512); \
    _Pragma("unroll") for (int ss = 0; ss < 4; ++ss) {                         \
      f32x4 st[4] = {};                                                        \
      _Pragma("unroll") for (int ni = 0; ni < 4; ++ni)                         \
        _Pragma("unroll") for (int kk = 0; kk < 2; ++kk)                       \
          st[ni] = mfma16(KS[ni * 2 + kk], qf[ss][kk], st[ni]);                \
      if (ss == 0 && (KT) + 1 < 16) {                                          \
        _Pragma("unroll") for (int i = 0; i < 8; ++i)                          \
          KN[i] = *(const bf16x8*)(Kb + (((KT) + 1) * 8 + i) * 512);           \
      }                                                                        \
      SM_PV(st, m_[ss], l_[ss], o[ss])                                         \
    }                                                                          \
  }

  for (int jj = 0; jj < 8; ++jj) {
    ATTN_TILE(kp, kq, jj * 2);
    ATTN_TILE(kq, kp, jj * 2 + 1);
  }
#undef ATTN_TILE
#undef SM_PV

  // Epilogue -> Ogf granule layout (4 sets; set ss occupies rowgroup rg0+ss).
  int b_ = bh >> 4, h = bh & 15;
  int rg0 = ((b_ << 10) + q0) >> 4;
#pragma unroll
  for (int ss = 0; ss < 4; ++ss) {
    float iv = 1.f / l_[ss];
#pragma unroll
    for (int od = 0; od < 4; ++od) {
      union { bf16_t b[4]; } pk;
#pragma unroll
      for (int r = 0; r < 4; ++r) pk.b[r] = (bf16_t)(o[ss][od][r] * iv);
      int kt2 = (h << 1) + (od >> 1);
      int lp = ((od & 1) * 2 + (hi >> 1)) * 16 + c;
      int el = (hi & 1) * 4;
      __builtin_memcpy(&Ogf[((size_t)((rg0 + ss) * 32 + kt2) * 64 + lp) * 8 + el],
                       pk.b, 8);
    }
  }
}

extern "C" void kernel_launch(void* const* d_in, const int* in_sizes, int n_in,
                              void* d_out, int out_size, void* d_ws, size_t ws_size,
                              hipStream_t stream) {
  const float* x = (const float*)d_in[0];
  const int* pos = (const int*)d_in[1];
  const float* Wq = (const float*)d_in[2];
  const float* bq = (const float*)d_in[3];
  const float* Wk = (const float*)d_in[4];
  const float* bk = (const float*)d_in[5];
  const float* Wv = (const float*)d_in[6];
  const float* bv = (const float*)d_in[7];
  const float* Wo = (const float*)d_in[8];
  const float* bo = (const float*)d_in[9];
  float* out = (float*)d_out;

  // ws: [0,16M) Xf (granule; reused as Ogf) | [16M,24M) Wf (granule)
  //     [24M,40M) Vg (V^T granule) | [42M,..) rope table.
  // Qh (row-major) + Kg (granule) live in d_out (16MB each).
  char* ws = (char*)d_ws;
  bf16_t* Xf = (bf16_t*)ws;
  bf16_t* Wf = (bf16_t*)(ws + (16u << 20));
  bf16_t* Vg = (bf16_t*)(ws + (24u << 20));
  float2* rt = (float2*)(ws + (42u << 20));
  bf16_t* Qh = (bf16_t*)d_out;
  bf16_t* Kg = (bf16_t*)d_out + (size_t)8 * 1024 * 1024;
  bf16_t* Ogf = Xf;

  k_prep<<<6272, 256, 0, stream>>>(x, Wq, Wk, Wv, Wo, pos, Xf, Wf, rt);
  k_gemm_qkv<<<768, 512, 0, stream>>>(Xf, Wf, bq, bk, bv, rt, Qh, Kg, Vg);
  k_attn<<<256, 512, 0, stream>>>(Qh, Kg, Vg, Ogf);
  k_gemm_out<<<256, 512, 0, stream>>>(Ogf, Wf, bo, out);
}

// Round 17
// 133.654 us; speedup vs baseline: 1.2333x; 1.0735x over previous
//
#include <hip/hip_runtime.h>
#include <hip/hip_bf16.h>

// Fused: QKV proj (+bias) -> RoPE(Q,K) -> MHA softmax -> out proj (+bias)
// B=8 S=1024 D=1024 H=16 Dk=64.
// R17 = R16 (best: 143.5us) with WIDER GEMM WAVES: 128x64 per wave
// (acc[8][4], 32 MFMA per 12 fragment loads = 2.67 MFMA/load vs 2.0)
// -> L2 fragment traffic x0.75. 4-wave/256-thr blocks (256x128 tile),
// same 768-block grid, same XCD m-chunk (producer/consumer-aligned).
// Attn (T13 defer-max) and prep unchanged from R16.

typedef __bf16 bf16_t;
typedef __bf16 bf16x8 __attribute__((ext_vector_type(8)));
typedef float  f32x4  __attribute__((ext_vector_type(4)));

static __device__ __forceinline__ f32x4 mfma16(bf16x8 a, bf16x8 b, f32x4 c) {
  return __builtin_amdgcn_mfma_f32_16x16x32_bf16(a, b, c, 0, 0, 0);
}

#if __has_builtin(__builtin_amdgcn_exp2f)
#define EXP2F(x) __builtin_amdgcn_exp2f(x)
#else
#define EXP2F(x) exp2f(x)
#endif

// ---------------- prep (single kernel): granule casts + rope table --------
__global__ void k_prep(const float* __restrict__ x, const float* __restrict__ Wq,
                       const float* __restrict__ Wk, const float* __restrict__ Wv,
                       const float* __restrict__ Wo, const int* __restrict__ pos,
                       bf16_t* __restrict__ Xf, bf16_t* __restrict__ Wf,
                       float2* __restrict__ rt) {
  const int bid = blockIdx.x;
  const int t = threadIdx.x;
  if (bid < 4096) {                     // x -> Xf granules (8192x1024)
    int g = bid * 256 + t;
    int rg = g >> 11, kt = (g >> 6) & 31, lane = g & 63;
    int m = rg * 16 + (lane & 15);
    int k = kt * 32 + (lane >> 4) * 8;
    const float* s = x + (size_t)m * 1024 + k;
    float4 v0 = *(const float4*)s;
    float4 v1 = *(const float4*)(s + 4);
    union { bf16_t b[8]; } pk;
    pk.b[0] = (bf16_t)v0.x; pk.b[1] = (bf16_t)v0.y; pk.b[2] = (bf16_t)v0.z; pk.b[3] = (bf16_t)v0.w;
    pk.b[4] = (bf16_t)v1.x; pk.b[5] = (bf16_t)v1.y; pk.b[6] = (bf16_t)v1.z; pk.b[7] = (bf16_t)v1.w;
    __builtin_memcpy(Xf + (size_t)g * 8, pk.b, 16);
  } else if (bid < 6144) {              // W -> Wf granules (rg: Wq|Wk|Wv|Wo)
    int g = (bid - 4096) * 256 + t;
    int rg = g >> 11, kt = (g >> 6) & 31, lane = g & 63;
    const float* src = (rg < 64) ? Wq : (rg < 128) ? Wk : (rg < 192) ? Wv : Wo;
    int row = (rg & 63) * 16 + (lane & 15);
    int k = kt * 32 + (lane >> 4) * 8;
    const float* s = src + (size_t)row * 1024 + k;
    float4 v0 = *(const float4*)s;
    float4 v1 = *(const float4*)(s + 4);
    union { bf16_t b[8]; } pk;
    pk.b[0] = (bf16_t)v0.x; pk.b[1] = (bf16_t)v0.y; pk.b[2] = (bf16_t)v0.z; pk.b[3] = (bf16_t)v0.w;
    pk.b[4] = (bf16_t)v1.x; pk.b[5] = (bf16_t)v1.y; pk.b[6] = (bf16_t)v1.z; pk.b[7] = (bf16_t)v1.w;
    __builtin_memcpy(Wf + (size_t)g * 8, pk.b, 16);
  } else {                              // rope table
    int rb = bid - 6144;                // [0,128)
    int s = rb * 8 + (t >> 5);
    int f = t & 31;
    float p = (float)pos[s];
    float inv = powf(10000.0f, -(float)(2 * f) / 64.0f);
    float a = p * inv;
    rt[s * 32 + f] = make_float2(cosf(a), sinf(a));
  }
}

// ==== R17 wide GEMM body: 256x128 tile, 4 waves (2M x 2N), wave=128x64 ====
// Per wave per BK=32 step: 8 A frags + 4 B frags (12KB), 32 MFMA. P/Q
// double-buffer (all indices compile-time unrolled -> registers, rule #20).
#define GEMM_WIDE_BODY(AfBase, BfBase)                                         \
  const int t = threadIdx.x;                                                   \
  const int lane = t & 63, w = t >> 6;          /* w in [0,4) */               \
  const int hi = lane >> 4, c = lane & 15;                                     \
  const int wm = w >> 1, wn = w & 1;                                           \
  const bf16_t* Ab = (AfBase) + (size_t)((i0 >> 4) + wm * 8) * 16384 + lane * 8; \
  const bf16_t* Bb = (BfBase) + (size_t)((e0 >> 4) + wn * 4) * 16384 + lane * 8; \
  bf16x8 pA[8], pB[4], qA[8], qB[4];                                           \
  f32x4 acc[8][4] = {};                                                        \
  auto loadP = [&](int kt) {                                                   \
    _Pragma("unroll") for (int f = 0; f < 8; ++f)                              \
      pA[f] = *(const bf16x8*)(Ab + (size_t)f * 16384 + kt * 512);             \
    _Pragma("unroll") for (int f = 0; f < 4; ++f)                              \
      pB[f] = *(const bf16x8*)(Bb + (size_t)f * 16384 + kt * 512);             \
  };                                                                           \
  auto loadQ = [&](int kt) {                                                   \
    _Pragma("unroll") for (int f = 0; f < 8; ++f)                              \
      qA[f] = *(const bf16x8*)(Ab + (size_t)f * 16384 + kt * 512);             \
    _Pragma("unroll") for (int f = 0; f < 4; ++f)                              \
      qB[f] = *(const bf16x8*)(Bb + (size_t)f * 16384 + kt * 512);             \
  };                                                                           \
  auto compP = [&]() {                                                         \
    __builtin_amdgcn_s_setprio(1);                                             \
    _Pragma("unroll") for (int fr = 0; fr < 8; ++fr)                           \
      _Pragma("unroll") for (int nc = 0; nc < 4; ++nc)                         \
        acc[fr][nc] = mfma16(pA[fr], pB[nc], acc[fr][nc]);                     \
    __builtin_amdgcn_s_setprio(0);                                             \
  };                                                                           \
  auto compQ = [&]() {                                                         \
    __builtin_amdgcn_s_setprio(1);                                             \
    _Pragma("unroll") for (int fr = 0; fr < 8; ++fr)                           \
      _Pragma("unroll") for (int nc = 0; nc < 4; ++nc)                         \
        acc[fr][nc] = mfma16(qA[fr], qB[nc], acc[fr][nc]);                     \
    __builtin_amdgcn_s_setprio(0);                                             \
  };                                                                           \
  loadP(0);                                                                    \
  loadQ(1);                                                                    \
  _Pragma("unroll 3")                                                          \
  for (int jj = 0; jj < 15; ++jj) {                                            \
    compP(); loadP(jj * 2 + 2);                                                \
    compQ(); loadQ(jj * 2 + 3);                                                \
  }                                                                            \
  compP();                                                                     \
  compQ();

// ---------------- fused QKV GEMM: N=3072, 768 blocks, XCD m-chunk ---------
// XCD x owns m [1024x,1024x+1024) = batch x (4 m-tiles of 256); m-fastest
// within XCD so 4 consecutive blocks share each 256KB B-tile; K/V writes
// land on the XCD whose attn reads them.
__global__ __launch_bounds__(256) void k_gemm_qkv(
    const bf16_t* __restrict__ Xf, const bf16_t* __restrict__ Wf,
    const float* __restrict__ bq, const float* __restrict__ bk,
    const float* __restrict__ bv, const float2* __restrict__ rt,
    bf16_t* __restrict__ Qh, bf16_t* __restrict__ Kg, bf16_t* __restrict__ Vg) {
  const int bid = blockIdx.x;
  const int x = bid & 7, q = bid >> 3;           // q in [0,96)
  const int i0 = (x * 4 + (q & 3)) * 256;
  const int e0 = (q >> 2) * 128;

  GEMM_WIDE_BODY(Xf, Wf)

  const int z = e0 >> 10;                       // 0:Q 1:K 2:V
  const int ez0 = (e0 & 1023) + wn * 64;        // multiple of 64 -> one head
  const int h = ez0 >> 6;
  const float* bias = (z == 0) ? bq : (z == 1) ? bk : bv;
  if (z == 2) {
    // V -> V^T granule (R12 ledger).
#pragma unroll
    for (int fr = 0; fr < 8; ++fr) {
      int i = i0 + wm * 128 + fr * 16 + hi * 4;
      int b_ = i >> 10, sbase = i & 1023;
      int bhv = b_ * 16 + h;
      int lane_ = c | (((sbase >> 3) & 3) << 4);
#pragma unroll
      for (int nc = 0; nc < 4; ++nc) {
        float bv_ = bias[ez0 + nc * 16 + c];
        union { bf16_t b[4]; } pk;
#pragma unroll
        for (int r = 0; r < 4; ++r) pk.b[r] = (bf16_t)(acc[fr][nc][r] + bv_);
        size_t g = (size_t)(bhv * 4 + nc) * 32 + (sbase >> 5);
        __builtin_memcpy(&Vg[g * 512 + lane_ * 8 + (sbase & 7)], pk.b, 8);
      }
    }
  } else if (z == 0) {
    // Q row-major with rope; folds 1/sqrt(64)*log2(e) (exp2-domain softmax).
    const float scl = 0.18033688011112042f;
#pragma unroll
    for (int fr = 0; fr < 8; ++fr) {
      int i = i0 + wm * 128 + fr * 16 + hi * 4;
      int b_ = i >> 10, sbase = i & 1023;
      size_t obase = (size_t)((b_ * 16 + h) * 1024);
#pragma unroll
      for (int nc = 0; nc < 2; ++nc) {          // f<32; partner f+32 = frag nc+2
        int f = nc * 16 + c;
        float b1_ = bias[ez0 + f], b2_ = bias[ez0 + f + 32];
#pragma unroll
        for (int r = 0; r < 4; ++r) {
          int s = sbase + r;
          float2 cs = rt[s * 32 + f];
          float q1 = acc[fr][nc][r] + b1_;
          float q2 = acc[fr][nc + 2][r] + b2_;
          Qh[(obase + s) * 64 + f] = (bf16_t)((q1 * cs.x - q2 * cs.y) * scl);
          Qh[(obase + s) * 64 + f + 32] = (bf16_t)((q1 * cs.y + q2 * cs.x) * scl);
        }
      }
    }
  } else {
    // K -> granule with rope (R12 ledger).
#pragma unroll
    for (int fr = 0; fr < 8; ++fr) {
      int i = i0 + wm * 128 + fr * 16 + hi * 4;
      int b_ = i >> 10, sbase = i & 1023;
      bf16_t* gb = Kg + (size_t)((b_ * 16 + h) * 64 + (sbase >> 4)) * 1024;
#pragma unroll
      for (int nc = 0; nc < 2; ++nc) {
        int f = nc * 16 + c;
        float b1_ = bias[ez0 + f], b2_ = bias[ez0 + f + 32];
        int laneHi = (nc * 2 + (c >> 3)) << 4;
#pragma unroll
        for (int r = 0; r < 4; ++r) {
          int s = sbase + r;
          float2 cs = rt[s * 32 + f];
          float q1 = acc[fr][nc][r] + b1_;
          float q2 = acc[fr][nc + 2][r] + b2_;
          size_t off = (size_t)((hi * 4 + r) | laneHi) * 8 + (c & 7);
          gb[off] = (bf16_t)(q1 * cs.x - q2 * cs.y);
          gb[off + 512] = (bf16_t)(q1 * cs.y + q2 * cs.x);
        }
      }
    }
  }
}

// ---------------- out projection: 256 blocks, same wide engine ------------
__global__ __launch_bounds__(256) void k_gemm_out(
    const bf16_t* __restrict__ Ogf, const bf16_t* __restrict__ Wf,
    const float* __restrict__ bo, float* __restrict__ out) {
  const int bid = blockIdx.x;
  const int x = bid & 7, q = bid >> 3;           // q in [0,32)
  const int i0 = (x * 4 + (q & 3)) * 256;
  const int e0 = (q >> 2) * 128;
  const bf16_t* WfO = Wf + (size_t)192 * 16384;

  GEMM_WIDE_BODY(Ogf, WfO)

#pragma unroll
  for (int fr = 0; fr < 8; ++fr) {
    int i = i0 + wm * 128 + fr * 16 + hi * 4;
#pragma unroll
    for (int nc = 0; nc < 4; ++nc) {
      int e = e0 + wn * 64 + nc * 16 + c;
      float bv_ = bo[e];
#pragma unroll
      for (int r = 0; r < 4; ++r)
        out[(size_t)(i + r) * 1024 + e] = acc[fr][nc][r] + bv_;
    }
  }
}

// ---------------- flash attention (R16: R13 shape + T13 defer-max) --------
__global__ __launch_bounds__(512) void k_attn(
    const bf16_t* __restrict__ Qh, const bf16_t* __restrict__ Kg,
    const bf16_t* __restrict__ Vg, bf16_t* __restrict__ Ogf) {
  __shared__ alignas(16) char PL[8][2048];
  const int t = threadIdx.x;
  const int lane = t & 63, w = t >> 6;
  const int hi = lane >> 4, c = lane & 15;
  const int bid = blockIdx.x;
  const int wg = (bid & 7) * 32 + (bid >> 3);    // XCD x -> bh [16x,16x+16)
  const int bh = wg >> 1, half = wg & 1;
  const int q0 = half * 512 + w * 64;
  const size_t qbase = (size_t)bh * 64 * 1024;

  const bf16_t* Kb = Kg + (size_t)bh * 65536 + lane * 8;
  const bf16_t* Vb = Vg + (size_t)bh * 65536 + lane * 8;

  bf16x8 qf[4][2];
#pragma unroll
  for (int ss = 0; ss < 4; ++ss)
#pragma unroll
    for (int kk = 0; kk < 2; ++kk)
      qf[ss][kk] = *(const bf16x8*)&Qh[qbase + (size_t)(q0 + ss * 16 + c) * 64 +
                                       kk * 32 + hi * 8];

  f32x4 o[4][4] = {};
  float m_[4] = {-1e30f, -1e30f, -1e30f, -1e30f};
  float l_[4] = {0.f, 0.f, 0.f, 0.f};
  char* const plw = &PL[w][0];

  bf16x8 kp[8], kq[8], vv[8];
#pragma unroll
  for (int i = 0; i < 8; ++i) kp[i] = *(const bf16x8*)(Kb + i * 512);

#define SM_PV(ST, M, L, O)                                                     \
  {                                                                            \
    float pmax = -1e30f;                                                       \
    _Pragma("unroll") for (int ni = 0; ni < 4; ++ni)                           \
      _Pragma("unroll") for (int r = 0; r < 4; ++r)                            \
        pmax = fmaxf(pmax, ST[ni][r]);                                         \
    pmax = fmaxf(pmax, __shfl_xor(pmax, 16));                                  \
    pmax = fmaxf(pmax, __shfl_xor(pmax, 32));                                  \
    if (!__all(pmax <= M + 8.0f)) {        /* T13 defer-max (THR=8) */         \
      float mn = fmaxf(M, pmax);                                               \
      float sc = EXP2F(M - mn);                                                \
      M = mn;                                                                  \
      L *= sc;                                                                 \
      _Pragma("unroll") for (int od = 0; od < 4; ++od)                         \
        _Pragma("unroll") for (int r = 0; r < 4; ++r) O[od][r] *= sc;          \
    }                                                                          \
    float psum = 0.f;                                                          \
    _Pragma("unroll") for (int ni = 0; ni < 4; ++ni) {                         \
      union { bf16_t b[4]; } pk;                                               \
      _Pragma("unroll") for (int r = 0; r < 4; ++r) {                          \
        float p = EXP2F(ST[ni][r] - M);                                        \
        psum += p;                                                             \
        pk.b[r] = (bf16_t)p;                                                   \
      }                                                                        \
      __builtin_memcpy(plw + (ni * 2 + (hi >> 1)) * 256 + c * 16 + (hi & 1) * 8, \
                       pk.b, 8);                                               \
    }                                                                          \
    psum += __shfl_xor(psum, 16);                                              \
    psum += __shfl_xor(psum, 32);                                              \
    L += psum;                                                                 \
    bf16x8 pa[2];                                                              \
    __builtin_memcpy(&pa[0], plw + lane * 16, 16);                             \
    __builtin_memcpy(&pa[1], plw + 1024 + lane * 16, 16);                      \
    _Pragma("unroll") for (int od = 0; od < 4; ++od)                           \
      _Pragma("unroll") for (int kk = 0; kk < 2; ++kk)                         \
        O[od] = mfma16(vv[od * 2 + kk], pa[kk], O[od]);                        \
  }

#define ATTN_TILE(KS, KN, KT)                                                  \
  {                                                                            \
    _Pragma("unroll") for (int i = 0; i < 8; ++i)                              \
      vv[i] = *(const bf16x8*)(Vb + ((i >> 1) * 32 + (KT) * 2 + (i & 1)) * 512); \
    _Pragma("unroll") for (int ss = 0; ss < 4; ++ss) {                         \
      f32x4 st[4] = {};                                                        \
      _Pragma("unroll") for (int ni = 0; ni < 4; ++ni)                         \
        _Pragma("unroll") for (int kk = 0; kk < 2; ++kk)                       \
          st[ni] = mfma16(KS[ni * 2 + kk], qf[ss][kk], st[ni]);                \
      if (ss == 0 && (KT) + 1 < 16) {                                          \
        _Pragma("unroll") for (int i = 0; i < 8; ++i)                          \
          KN[i] = *(const bf16x8*)(Kb + (((KT) + 1) * 8 + i) * 512);           \
      }                                                                        \
      SM_PV(st, m_[ss], l_[ss], o[ss])                                         \
    }                                                                          \
  }

  for (int jj = 0; jj < 8; ++jj) {
    ATTN_TILE(kp, kq, jj * 2);
    ATTN_TILE(kq, kp, jj * 2 + 1);
  }
#undef ATTN_TILE
#undef SM_PV

  // Epilogue -> Ogf granule layout (4 sets; set ss occupies rowgroup rg0+ss).
  int b_ = bh >> 4, h = bh & 15;
  int rg0 = ((b_ << 10) + q0) >> 4;
#pragma unroll
  for (int ss = 0; ss < 4; ++ss) {
    float iv = 1.f / l_[ss];
#pragma unroll
    for (int od = 0; od < 4; ++od) {
      union { bf16_t b[4]; } pk;
#pragma unroll
      for (int r = 0; r < 4; ++r) pk.b[r] = (bf16_t)(o[ss][od][r] * iv);
      int kt2 = (h << 1) + (od >> 1);
      int lp = ((od & 1) * 2 + (hi >> 1)) * 16 + c;
      int el = (hi & 1) * 4;
      __builtin_memcpy(&Ogf[((size_t)((rg0 + ss) * 32 + kt2) * 64 + lp) * 8 + el],
                       pk.b, 8);
    }
  }
}

extern "C" void kernel_launch(void* const* d_in, const int* in_sizes, int n_in,
                              void* d_out, int out_size, void* d_ws, size_t ws_size,
                              hipStream_t stream) {
  const float* x = (const float*)d_in[0];
  const int* pos = (const int*)d_in[1];
  const float* Wq = (const float*)d_in[2];
  const float* bq = (const float*)d_in[3];
  const float* Wk = (const float*)d_in[4];
  const float* bk = (const float*)d_in[5];
  const float* Wv = (const float*)d_in[6];
  const float* bv = (const float*)d_in[7];
  const float* Wo = (const float*)d_in[8];
  const float* bo = (const float*)d_in[9];
  float* out = (float*)d_out;

  // ws: [0,16M) Xf (granule; reused as Ogf) | [16M,24M) Wf (granule)
  //     [24M,40M) Vg (V^T granule) | [42M,..) rope table.
  // Qh (row-major) + Kg (granule) live in d_out (16MB each).
  char* ws = (char*)d_ws;
  bf16_t* Xf = (bf16_t*)ws;
  bf16_t* Wf = (bf16_t*)(ws + (16u << 20));
  bf16_t* Vg = (bf16_t*)(ws + (24u << 20));
  float2* rt = (float2*)(ws + (42u << 20));
  bf16_t* Qh = (bf16_t*)d_out;
  bf16_t* Kg = (bf16_t*)d_out + (size_t)8 * 1024 * 1024;
  bf16_t* Ogf = Xf;

  k_prep<<<6272, 256, 0, stream>>>(x, Wq, Wk, Wv, Wo, pos, Xf, Wf, rt);
  k_gemm_qkv<<<768, 256, 0, stream>>>(Xf, Wf, bq, bk, bv, rt, Qh, Kg, Vg);
  k_attn<<<256, 512, 0, stream>>>(Qh, Kg, Vg, Ogf);
  k_gemm_out<<<256, 256, 0, stream>>>(Ogf, Wf, bo, out);
}